// Round 3
// baseline (320.513 us; speedup 1.0000x reference)
//
#include <hip/hip_runtime.h>
#include <hip/hip_fp16.h>

#define TT   4096
#define NTH  512
// skew: +2 per 16 elements -> stage writes <=2-way bank aliasing, loads <=3-way
#define SK(e) ((e) + (((e) >> 4) << 1))
#define ARR  4608                       // SK(4095)=4605
#define SM_FLOATS (4*ARR + 1152 + 44)   // A,B (re/im) + 2x hist + res
#define SM_BYTES  (SM_FLOATS * 4)

__device__ __forceinline__ float centerF(int k){
    return (float)(-0.5 + (double)k * (1.0/7.0));
}
__device__ __forceinline__ float freq_of(int m){
    return (float)((m < TT/2) ? m : (m - TT)) * (1.0f/(float)TT);
}
__device__ __forceinline__ float filtv(float f, float ck){
    float d = (f - ck) * 8.0f;
    return __expf(-0.5f * d * d);
}
// G_k[m] = (F_k[m] + F_k[N-m]) * 0.5/N   (Hermitian-input shortcut, includes 1/N)
__device__ __forceinline__ float Gval(int m, float ck){
    int mm = (TT - m) & (TT - 1);
    return (filtv(freq_of(m), ck) + filtv(freq_of(mm), ck)) * (0.5f/(float)TT);
}

struct C4 { float r0,i0,r1,i1,r2,i2,r3,i3; };

// radix-4 DIT butterfly; u = e^{+i*pi*kk/(2Ns)} (inverse-sign); SGN=-1 => fwd (conj applied inside)
template<int SGN>
__device__ __forceinline__ void bf4(float c0r,float c0i,float c1r,float c1i,
                                    float c2r,float c2i,float c3r,float c3i,
                                    float ur,float ui, C4& o){
    float u2r = ur*ur - ui*ui, u2i = 2.f*ur*ui;
    float u3r = u2r*ur - u2i*ui, u3i = u2r*ui + u2i*ur;
    if (SGN < 0){ ui = -ui; u2i = -u2i; u3i = -u3i; }
    float ar = u2r*c2r - u2i*c2i, ai = u2r*c2i + u2i*c2r;
    float br = ur*c1r  - ui*c1i,  bi = ur*c1i  + ui*c1r;
    float er = u3r*c3r - u3i*c3i, ei = u3r*c3i + u3i*c3r;
    float s0r = c0r+ar, s0i = c0i+ai, s1r = c0r-ar, s1i = c0i-ai;
    float s2r = br+er,  s2i = bi+ei,  s3r = br-er,  s3i = bi-ei;
    o.r0 = s0r+s2r; o.i0 = s0i+s2i;
    o.r2 = s0r-s2r; o.i2 = s0i-s2i;
    if (SGN > 0){ o.r1 = s1r-s3i; o.i1 = s1i+s3r; o.r3 = s1r+s3i; o.i3 = s1i-s3r; }
    else        { o.r1 = s1r+s3i; o.i1 = s1i-s3r; o.r3 = s1r-s3i; o.i3 = s1i+s3r; }
}

template<int SGN>
__device__ __forceinline__ void stageLDS(const float* __restrict__ sr, const float* __restrict__ si,
                                         float* __restrict__ dr, float* __restrict__ di,
                                         int Ns, float uAr,float uAi,float uBr,float uBi, int tid){
#pragma unroll
    for (int h = 0; h < 2; ++h){
        int j = tid + h*512;
        float ur = h ? uBr : uAr, ui = h ? uBi : uAi;
        int kk = j & (Ns-1);
        int base = ((j & ~(Ns-1)) << 2) | kk;
        C4 o;
        bf4<SGN>(sr[SK(j)],si[SK(j)], sr[SK(j+1024)],si[SK(j+1024)],
                 sr[SK(j+2048)],si[SK(j+2048)], sr[SK(j+3072)],si[SK(j+3072)], ur,ui,o);
        dr[SK(base)]       = o.r0;  di[SK(base)]       = o.i0;
        dr[SK(base+Ns)]    = o.r1;  di[SK(base+Ns)]    = o.i1;
        dr[SK(base+2*Ns)]  = o.r2;  di[SK(base+2*Ns)]  = o.i2;
        dr[SK(base+3*Ns)]  = o.r3;  di[SK(base+3*Ns)]  = o.i3;
    }
}

__device__ __forceinline__ int wt_of(int r){ return r==0 ? 6 : (r==1 ? 2 : (r==2 ? 1 : 0)); }

// Lehmer code of stable argsort — register-only, 6 compares (verified round 1)
__device__ __forceinline__ int pattern_id(float v0, float v1, float v2, float v3){
    int c01 = (v0 <= v1), c02 = (v0 <= v2), c03 = (v0 <= v3);
    int c12 = (v1 <= v2), c13 = (v1 <= v3), c23 = (v2 <= v3);
    int r1 = c01 + (1-c12) + (1-c13);
    int r2 = c02 + c12 + (1-c23);
    int r3 = c03 + c13 + c23;
    int g1 = 1 - c01;
    int g2 = (1-c02) + (1-c12);
    int g3 = (1-c03) + (1-c13) + (1-c23);
    return wt_of(r1)*g1 + wt_of(r2)*g2 + wt_of(r3)*g3;
}

__device__ __forceinline__ int DIDX(int k, int l){   // res index of D_kl, k<=l
    return 8 + k*8 + l - (k*(k+1))/2;
}

__device__ __forceinline__ void reduce_to(float v, float* res, int idx, int tid){
#pragma unroll
    for (int off = 32; off; off >>= 1) v += __shfl_xor(v, off);
    if ((tid & 63) == 0) atomicAdd(&res[idx], v);
}

template<int P>
__device__ __forceinline__ void process_pair(int tid,
        float* Ar, float* Ai, float* Br, float* Bi,
        unsigned* hist, float* res,
        const float (&xr)[8], const float (&xi)[8],
        __half2 (&est)[6][4],
        float t4r,float t4i,float t16r,float t16i,float t64r,float t64i,
        float t256r,float t256i,float tAr,float tAi,float tBr,float tBi){
    const float ck0 = centerF(2*P), ck1 = centerF(2*P+1);

    // stage 0 (Ns=1): registers (X * (G0 + i*G1)) -> A
#pragma unroll
    for (int h = 0; h < 2; ++h){
        int j = tid + h*512;
        float cr[4], ci[4];
#pragma unroll
        for (int q = 0; q < 4; ++q){
            int v = 2*q + h;
            int m = j + 1024*q;
            float g0 = Gval(m, ck0), g1 = Gval(m, ck1);
            cr[q] = xr[v]*g0 - xi[v]*g1;
            ci[q] = xi[v]*g0 + xr[v]*g1;
        }
        C4 o; bf4<1>(cr[0],ci[0],cr[1],ci[1],cr[2],ci[2],cr[3],ci[3], 1.f,0.f, o);
        int base = 4*j;
        Ar[SK(base)]   = o.r0;  Ai[SK(base)]   = o.i0;
        Ar[SK(base+1)] = o.r1;  Ai[SK(base+1)] = o.i1;
        Ar[SK(base+2)] = o.r2;  Ai[SK(base+2)] = o.i2;
        Ar[SK(base+3)] = o.r3;  Ai[SK(base+3)] = o.i3;
    }
    __syncthreads();
    stageLDS<1>(Ar,Ai,Br,Bi,    4, t4r,t4i,t4r,t4i, tid);       __syncthreads();
    stageLDS<1>(Br,Bi,Ar,Ai,   16, t16r,t16i,t16r,t16i, tid);   __syncthreads();
    stageLDS<1>(Ar,Ai,Br,Bi,   64, t64r,t64i,t64r,t64i, tid);   __syncthreads();
    stageLDS<1>(Br,Bi,Ar,Ai,  256, t256r,t256i,t256r,t256i, tid); __syncthreads();
    stageLDS<1>(Ar,Ai,Br,Bi, 1024, tAr,tAi,tBr,tBi, tid);       __syncthreads();
    // modes: k0 = Br[t], k1 = Bi[t];  A is now free -> pid scratch

    int* pidR = (int*)Ar;
    int* pidI = (int*)Ai;

    float aS0=0.f, aS1=0.f, aD00=0.f, aD11=0.f, aD01=0.f;
    float aX[(P > 0) ? 4*P : 1];
#pragma unroll
    for (int i = 0; i < ((P>0)?4*P:1); ++i) aX[i] = 0.f;

    float carry0 = 0.f, carry1 = 0.f;
#pragma unroll
    for (int u = 0; u < 8; ++u){
        int t  = tid + u*NTH;
        int t1 = (t+1 < TT) ? t+1 : TT-1;
        int t2 = (t+2 < TT) ? t+2 : TT-1;
        int t3 = (t+3 < TT) ? t+3 : TT-1;
        float b0 = Br[SK(t)], b1 = Br[SK(t1)], b2 = Br[SK(t2)], b3 = Br[SK(t3)];
        float i0 = Bi[SK(t)], i1 = Bi[SK(t1)], i2 = Bi[SK(t2)], i3 = Bi[SK(t3)];
        float e0 = b0*b0, e1 = i0*i0;
        aS0 += e0; aS1 += e1;
        aD00 += e0*e0; aD11 += e1*e1; aD01 += e0*e1;
#pragma unroll
        for (int l = 0; l < 2*P; ++l){
            float el = (u & 1) ? __high2float(est[l][u>>1]) : __low2float(est[l][u>>1]);
            aX[2*l]   += el * e0;
            aX[2*l+1] += el * e1;
        }
        if constexpr (P < 3){
            if ((u & 1) == 0){ carry0 = e0; carry1 = e1; }
            else {
                est[2*P][u>>1]   = __floats2half2_rn(carry0, e0);
                est[2*P+1][u>>1] = __floats2half2_rn(carry1, e1);
            }
        }
        if (t <= TT-4){
            pidR[t] = pattern_id(b0,b1,b2,b3);
            pidI[t] = pattern_id(i0,i1,i2,i3);
        }
    }
    __syncthreads();

    // run-length-merged histogram atomics (periodic edge modes collapse to ~1 atomic)
    {
        unsigned* h = hist + 576*((tid>>6) & 1);
        int curR = -1, curI = -1; unsigned cR = 0, cI = 0;
#pragma unroll
        for (int u = 0; u < 8; ++u){
            int t = tid + u*NTH;
            if (t <= TT-5){
                int lr = pidR[t]*24 + pidR[t+1];
                if (lr == curR) cR++;
                else { if (cR) atomicAdd(&h[curR], cR); curR = lr; cR = 1; }
                int li = pidI[t]*24 + pidI[t+1];
                if (li == curI) cI++;
                else { if (cI) atomicAdd(&h[curI], cI); curI = li; cI = 1; }
            }
        }
        if (cR) atomicAdd(&h[curR], cR);
        if (cI) atomicAdd(&h[curI], cI);
    }
    __syncthreads();   // protects pid buffers (A) before next pair's stage-0 writes

    const int k0 = 2*P, k1 = 2*P+1;
    reduce_to(aS0,  res, k0, tid);
    reduce_to(aS1,  res, k1, tid);
    reduce_to(aD00, res, DIDX(k0,k0), tid);
    reduce_to(aD11, res, DIDX(k1,k1), tid);
    reduce_to(aD01, res, DIDX(k0,k1), tid);
#pragma unroll
    for (int l = 0; l < 2*P; ++l){
        reduce_to(aX[2*l],   res, DIDX(l,k0), tid);
        reduce_to(aX[2*l+1], res, DIDX(l,k1), tid);
    }
}

template<bool DIRECT>
__global__ __launch_bounds__(NTH)
__attribute__((amdgpu_waves_per_eu(4,4)))   // pin 4 waves/EU: 128-VGPR cap, no spill chase
void fused_kernel(const float* __restrict__ hs, const float* __restrict__ pooled,
                  float* __restrict__ out){
    extern __shared__ float smem[];
    float* Ar = smem;
    float* Ai = smem + ARR;
    float* Br = smem + 2*ARR;
    float* Bi = smem + 3*ARR;
    unsigned* hist = (unsigned*)(smem + 4*ARR);   // 2 x 576
    float* res = smem + 4*ARR + 1152;             // 44

    const int tid = threadIdx.x;
    const int bg = blockIdx.x, b = bg >> 5, g = bg & 31;

    for (int i = tid; i < 1152; i += NTH) hist[i] = 0u;
    if (tid < 44) res[tid] = 0.f;

    // per-thread twiddles, inverse sign: u = e^{+i*pi*kk/(2Ns)}; kk fixed per thread per stage
    const float PI_F = 3.14159265358979323846f;
    float t4r,t4i,t16r,t16i,t64r,t64i,t256r,t256i,tAr,tAi,tBr,tBi;
    { float s,c;
      __sincosf(PI_F*(float)(tid &   3)/   8.f, &s,&c); t4r=c;   t4i=s;
      __sincosf(PI_F*(float)(tid &  15)/  32.f, &s,&c); t16r=c;  t16i=s;
      __sincosf(PI_F*(float)(tid &  63)/ 128.f, &s,&c); t64r=c;  t64i=s;
      __sincosf(PI_F*(float)(tid & 255)/ 512.f, &s,&c); t256r=c; t256i=s;
      __sincosf(PI_F*(float)tid        /2048.f, &s,&c); tAr=c;   tAi=s;
      __sincosf(PI_F*(float)(tid+512)  /2048.f, &s,&c); tBr=c;   tBi=s;
    }

    // load signal -> A (skewed)
    if (DIRECT){
        const float* base = hs + ((size_t)b * TT) * 512 + g * 16;
#pragma unroll
        for (int u = 0; u < 8; ++u){
            int t = tid + u*NTH;
            const float4* p = (const float4*)(base + (size_t)t * 512);
            float4 a = p[0], bb = p[1], cc = p[2], dd = p[3];
            float s = a.x+a.y+a.z+a.w + bb.x+bb.y+bb.z+bb.w
                    + cc.x+cc.y+cc.z+cc.w + dd.x+dd.y+dd.z+dd.w;
            Ar[SK(t)] = s * (1.0f/16.0f);
            Ai[SK(t)] = 0.f;
        }
    } else {
        const float* pp = pooled + (size_t)bg * TT;
#pragma unroll
        for (int u = 0; u < 8; ++u){
            int t = tid + u*NTH;
            Ar[SK(t)] = pp[t];
            Ai[SK(t)] = 0.f;
        }
    }
    __syncthreads();

    // forward FFT (SGN=-1): 6 radix-4 stages; final stage lands the spectrum in registers
    stageLDS<-1>(Ar,Ai,Br,Bi,   1, 1.f,0.f,1.f,0.f, tid);        __syncthreads();
    stageLDS<-1>(Br,Bi,Ar,Ai,   4, t4r,t4i,t4r,t4i, tid);        __syncthreads();
    stageLDS<-1>(Ar,Ai,Br,Bi,  16, t16r,t16i,t16r,t16i, tid);    __syncthreads();
    stageLDS<-1>(Br,Bi,Ar,Ai,  64, t64r,t64i,t64r,t64i, tid);    __syncthreads();
    stageLDS<-1>(Ar,Ai,Br,Bi, 256, t256r,t256i,t256r,t256i, tid);__syncthreads();

    float xr[8], xi[8];   // X[tid + 512*v]
    {
        C4 o;
        bf4<-1>(Br[SK(tid)],Bi[SK(tid)], Br[SK(tid+1024)],Bi[SK(tid+1024)],
                Br[SK(tid+2048)],Bi[SK(tid+2048)], Br[SK(tid+3072)],Bi[SK(tid+3072)],
                tAr,tAi,o);
        xr[0]=o.r0; xi[0]=o.i0; xr[2]=o.r1; xi[2]=o.i1;
        xr[4]=o.r2; xi[4]=o.i2; xr[6]=o.r3; xi[6]=o.i3;
        bf4<-1>(Br[SK(tid+512)],Bi[SK(tid+512)], Br[SK(tid+1536)],Bi[SK(tid+1536)],
                Br[SK(tid+2560)],Bi[SK(tid+2560)], Br[SK(tid+3584)],Bi[SK(tid+3584)],
                tBr,tBi,o);
        xr[1]=o.r0; xi[1]=o.i0; xr[3]=o.r1; xi[3]=o.i1;
        xr[5]=o.r2; xi[5]=o.i2; xr[7]=o.r3; xi[7]=o.i3;
    }
    // no sync needed: A's last reader (Ns=256 stage) is behind a barrier; pair-0 writes A next

    __half2 est[6][4];
    process_pair<0>(tid,Ar,Ai,Br,Bi,hist,res,xr,xi,est,t4r,t4i,t16r,t16i,t64r,t64i,t256r,t256i,tAr,tAi,tBr,tBi);
    process_pair<1>(tid,Ar,Ai,Br,Bi,hist,res,xr,xi,est,t4r,t4i,t16r,t16i,t64r,t64i,t256r,t256i,tAr,tAi,tBr,tBi);
    process_pair<2>(tid,Ar,Ai,Br,Bi,hist,res,xr,xi,est,t4r,t4i,t16r,t16i,t64r,t64i,t256r,t256i,tAr,tAi,tBr,tBi);
    process_pair<3>(tid,Ar,Ai,Br,Bi,hist,res,xr,xi,est,t4r,t4i,t16r,t16i,t64r,t64i,t256r,t256i,tAr,tAi,tBr,tBi);

    __syncthreads();   // res atomics + hist complete

    float* tm = out + (size_t)bg * 576;
    for (int i = tid; i < 576; i += NTH)
        tm[i] = (float)(hist[i] + hist[i+576]) * (1.0f/32736.0f);

    if (tid < 28){
        int q = tid, k = 0, cnt = 7, rem = q;
        while (rem >= cnt){ rem -= cnt; k++; cnt--; }
        int l = k + 1 + rem;
        float Sk = res[k], Sl = res[l];
        float Dkl = res[DIDX(k,l)], Dkk = res[DIDX(k,k)], Dll = res[DIDX(l,l)];
        float cov = Dkl - Sk*Sl*(1.0f/4096.0f);
        float vk = (Dkk - Sk*Sk*(1.0f/4096.0f)) * (1.0f/4095.0f);
        float vl = (Dll - Sl*Sl*(1.0f/4096.0f)) * (1.0f/4095.0f);
        float sk = fmaxf(sqrtf(fmaxf(vk, 0.f)), 1e-8f);
        float sl = fmaxf(sqrtf(fmaxf(vl, 0.f)), 1e-8f);
        out[294912 + (size_t)bg*28 + q] = cov * (1.0f/4096.0f) / (sk*sl);
    }
}

// Coalesced pooling: [B,T,512] -> [B,G,T] group means (unchanged, verified round 1)
__global__ __launch_bounds__(256)
void pool_kernel(const float* __restrict__ hs, float* __restrict__ pooled){
    __shared__ float tile[32][65];
    int blk = blockIdx.x;               // 16 b * 64 chunks
    int b   = blk >> 6;
    int t0  = (blk & 63) << 6;
    int tid = threadIdx.x;
    int lane = tid & 63, wid = tid >> 6;
#pragma unroll
    for (int i = 0; i < 16; ++i){
        int tl = wid + i*4;
        int t  = t0 + tl;
        const float4* p = (const float4*)(hs + ((size_t)b * TT + t) * 512);
        float4 a = p[lane];
        float4 c = p[lane + 64];
        float pa = a.x+a.y+a.z+a.w;
        float pc = c.x+c.y+c.z+c.w;
        pa += __shfl_xor(pa, 1); pa += __shfl_xor(pa, 2);
        pc += __shfl_xor(pc, 1); pc += __shfl_xor(pc, 2);
        if ((lane & 3) == 0){
            int gq = lane >> 2;
            tile[gq][tl]      = pa * (1.0f/16.0f);
            tile[gq + 16][tl] = pc * (1.0f/16.0f);
        }
    }
    __syncthreads();
    for (int idx = tid; idx < 2048; idx += 256){
        int g = idx >> 6, tt = idx & 63;
        pooled[((size_t)b * 32 + g) * TT + t0 + tt] = tile[g][tt];
    }
}

extern "C" void kernel_launch(void* const* d_in, const int* in_sizes, int n_in,
                              void* d_out, int out_size, void* d_ws, size_t ws_size,
                              hipStream_t stream){
    const float* hs = (const float*)d_in[0];
    float* out = (float*)d_out;
    const size_t poolBytes = (size_t)512 * TT * sizeof(float);   // 8.4 MB

    if (d_ws && ws_size >= poolBytes){
        float* pooled = (float*)d_ws;
        pool_kernel<<<1024, 256, 0, stream>>>(hs, pooled);
        hipFuncSetAttribute((const void*)fused_kernel<false>,
                            hipFuncAttributeMaxDynamicSharedMemorySize, SM_BYTES);
        fused_kernel<false><<<512, NTH, SM_BYTES, stream>>>(hs, pooled, out);
    } else {
        hipFuncSetAttribute((const void*)fused_kernel<true>,
                            hipFuncAttributeMaxDynamicSharedMemorySize, SM_BYTES);
        fused_kernel<true><<<512, NTH, SM_BYTES, stream>>>(hs, nullptr, out);
    }
}

// Round 5
// 291.328 us; speedup vs baseline: 1.1002x; 1.1002x over previous
//
#include <hip/hip_runtime.h>
#include <hip/hip_fp16.h>

#define TT   4096
#define NTH  512
#define SK(e) ((e) + ((e) >> 5))       // round-2 skew (verified best so far)
#define ARR  4224                      // SK(4095)=4222
#define SM_FLOATS (4*ARR + 1152 + 44)  // A,B (re/im) + 2x hist + res
#define SM_BYTES  (SM_FLOATS * 4)

__device__ __forceinline__ float centerF(int k){
    return (float)(-0.5 + (double)k * (1.0/7.0));
}
__device__ __forceinline__ float freq_of(int m){
    return (float)((m < TT/2) ? m : (m - TT)) * (1.0f/(float)TT);
}
__device__ __forceinline__ float filtv(float f, float ck){
    float d = (f - ck) * 8.0f;
    return __expf(-0.5f * d * d);
}
// G_k[m] = (F_k[m] + F_k[N-m]) * 0.5/N  (Hermitian-input shortcut, includes 1/N)
__device__ __forceinline__ float Gval(int m, float ck){
    int mm = (TT - m) & (TT - 1);
    return (filtv(freq_of(m), ck) + filtv(freq_of(mm), ck)) * (0.5f/(float)TT);
}

// ---------- radix-8 butterfly: y_m = sum_q c_q e^{SGN*2pi*i*mq/8} ----------
template<int SGN>
__device__ __forceinline__ void bf8(float (&xr)[8], float (&xi)[8]){
    const float C = 0.7071067811865476f;
    float tr[4], ti[4], ur[4], ui[4];
#pragma unroll
    for (int p = 0; p < 4; ++p){
        tr[p] = xr[p] + xr[p+4]; ti[p] = xi[p] + xi[p+4];
        ur[p] = xr[p] - xr[p+4]; ui[p] = xi[p] - xi[p+4];
    }
    float vr[4], vi[4];
    vr[0] = ur[0]; vi[0] = ui[0];
    if (SGN > 0){
        vr[1] =  C*(ur[1] - ui[1]); vi[1] =  C*(ur[1] + ui[1]);
        vr[2] = -ui[2];             vi[2] =  ur[2];
        vr[3] = -C*(ur[3] + ui[3]); vi[3] =  C*(ur[3] - ui[3]);
    } else {
        vr[1] =  C*(ur[1] + ui[1]); vi[1] =  C*(ui[1] - ur[1]);
        vr[2] =  ui[2];             vi[2] = -ur[2];
        vr[3] =  C*(ui[3] - ur[3]); vi[3] = -C*(ur[3] + ui[3]);
    }
    {   // DFT4 on t -> even outputs
        float s0r=tr[0]+tr[2], s0i=ti[0]+ti[2], s1r=tr[0]-tr[2], s1i=ti[0]-ti[2];
        float s2r=tr[1]+tr[3], s2i=ti[1]+ti[3], s3r=tr[1]-tr[3], s3i=ti[1]-ti[3];
        xr[0]=s0r+s2r; xi[0]=s0i+s2i;
        xr[4]=s0r-s2r; xi[4]=s0i-s2i;
        if (SGN > 0){ xr[2]=s1r-s3i; xi[2]=s1i+s3r; xr[6]=s1r+s3i; xi[6]=s1i-s3r; }
        else        { xr[2]=s1r+s3i; xi[2]=s1i-s3r; xr[6]=s1r-s3i; xi[6]=s1i+s3r; }
    }
    {   // DFT4 on v -> odd outputs
        float s0r=vr[0]+vr[2], s0i=vi[0]+vi[2], s1r=vr[0]-vr[2], s1i=vi[0]-vi[2];
        float s2r=vr[1]+vr[3], s2i=vi[1]+vi[3], s3r=vr[1]-vr[3], s3i=vi[1]-vi[3];
        xr[1]=s0r+s2r; xi[1]=s0i+s2i;
        xr[5]=s0r-s2r; xi[5]=s0i-s2i;
        if (SGN > 0){ xr[3]=s1r-s3i; xi[3]=s1i+s3r; xr[7]=s1r+s3i; xi[7]=s1i-s3r; }
        else        { xr[3]=s1r+s3i; xi[3]=s1i-s3r; xr[7]=s1r-s3i; xi[7]=s1i+s3r; }
    }
}

// apply w^q to element q (q=1..7), w given with desired sign
__device__ __forceinline__ void twid8(float (&xr)[8], float (&xi)[8], float wr, float wi){
    float pr = wr, pi = wi;
#pragma unroll
    for (int q = 1; q < 8; ++q){
        float ar = xr[q], ai = xi[q];
        xr[q] = ar*pr - ai*pi;
        xi[q] = ar*pi + ai*pr;
        float nr = pr*wr - pi*wi;
        float ni = pr*wi + pi*wr;
        pr = nr; pi = ni;
    }
}

// one LDS->LDS Stockham radix-8 stage
template<int SGN, int NS>
__device__ __forceinline__ void stage8(const float* __restrict__ sr, const float* __restrict__ si,
                                       float* __restrict__ dr, float* __restrict__ di,
                                       float wr, float wi, int tid){
    float xr[8], xi[8];
#pragma unroll
    for (int q = 0; q < 8; ++q){
        xr[q] = sr[SK(tid + 512*q)];
        xi[q] = si[SK(tid + 512*q)];
    }
    if (NS > 1) twid8(xr, xi, wr, wi);
    bf8<SGN>(xr, xi);
    int kk = tid & (NS-1);
    int base = ((tid & ~(NS-1)) << 3) | kk;
#pragma unroll
    for (int m = 0; m < 8; ++m){
        dr[SK(base + m*NS)] = xr[m];
        di[SK(base + m*NS)] = xi[m];
    }
}

__device__ __forceinline__ int wt_of(int r){ return r==0 ? 6 : (r==1 ? 2 : (r==2 ? 1 : 0)); }

// Lehmer code of stable argsort — register-only, 6 compares (verified rounds 1-3)
__device__ __forceinline__ int pattern_id(float v0, float v1, float v2, float v3){
    int c01 = (v0 <= v1), c02 = (v0 <= v2), c03 = (v0 <= v3);
    int c12 = (v1 <= v2), c13 = (v1 <= v3), c23 = (v2 <= v3);
    int r1 = c01 + (1-c12) + (1-c13);
    int r2 = c02 + c12 + (1-c23);
    int r3 = c03 + c13 + c23;
    int g1 = 1 - c01;
    int g2 = (1-c02) + (1-c12);
    int g3 = (1-c03) + (1-c13) + (1-c23);
    return wt_of(r1)*g1 + wt_of(r2)*g2 + wt_of(r3)*g3;
}

__device__ __forceinline__ int DIDX(int k, int l){   // res index of D_kl, k<=l
    return 8 + k*8 + l - (k*(k+1))/2;
}

__device__ __forceinline__ void reduce_to(float v, float* res, int idx, int tid){
#pragma unroll
    for (int off = 32; off; off >>= 1) v += __shfl_xor(v, off);
    if ((tid & 63) == 0) atomicAdd(&res[idx], v);
}

template<int P>
__device__ __forceinline__ void process_pair(int tid,
        float* Ar, float* Ai, float* Br, float* Bi,
        unsigned* hist, float* res,
        const float (&xr)[8], const float (&xi)[8],
        __half2 (&est)[6][4],
        float w8r,float w8i,float w64r,float w64i,float w512r,float w512i){
    const float ck0 = centerF(2*P), ck1 = centerF(2*P+1);

    // stage Ns=1 (kk=0, no twiddle): register spectrum * (G0 + i*G1) -> A
    {
        float cr[8], ci[8];
#pragma unroll
        for (int q = 0; q < 8; ++q){
            int m = tid + 512*q;
            float g0 = Gval(m, ck0), g1 = Gval(m, ck1);
            cr[q] = xr[q]*g0 - xi[q]*g1;
            ci[q] = xi[q]*g0 + xr[q]*g1;
        }
        bf8<1>(cr, ci);
        int base = 8*tid;
#pragma unroll
        for (int m = 0; m < 8; ++m){
            Ar[SK(base+m)] = cr[m];
            Ai[SK(base+m)] = ci[m];
        }
    }
    __syncthreads();
    stage8<1,8>(Ar,Ai,Br,Bi, w8r,w8i, tid);    __syncthreads();
    stage8<1,64>(Br,Bi,Ar,Ai, w64r,w64i, tid); __syncthreads();

    // last stage Ns=512: A -> registers (thread-local); modes at t = tid+512m
    float yr[8], yi[8];
#pragma unroll
    for (int q = 0; q < 8; ++q){
        yr[q] = Ar[SK(tid + 512*q)];
        yi[q] = Ai[SK(tid + 512*q)];
    }
    twid8(yr, yi, w512r, w512i);
    bf8<1>(yr, yi);
    // store modes to B for cross-thread window reads (B free: its last read was
    // the Ns=64 stage, behind the barrier above)
#pragma unroll
    for (int m = 0; m < 8; ++m){
        int t = tid + 512*m;
        Br[SK(t)] = yr[m];
        Bi[SK(t)] = yi[m];
    }
    __syncthreads();   // B writes visible; A reads (this pair) done -> pids may overwrite A

    int* pidR = (int*)Ar;
    int* pidI = (int*)Ai;

    float aS0=0.f, aS1=0.f, aD00=0.f, aD11=0.f, aD01=0.f;
    float aX[(P > 0) ? 4*P : 1];
#pragma unroll
    for (int i = 0; i < ((P>0)?4*P:1); ++i) aX[i] = 0.f;

    float carry0 = 0.f, carry1 = 0.f;
#pragma unroll
    for (int u = 0; u < 8; ++u){
        int t  = tid + 512*u;
        int t1 = (t+1 < TT) ? t+1 : TT-1;
        int t2 = (t+2 < TT) ? t+2 : TT-1;
        int t3 = (t+3 < TT) ? t+3 : TT-1;
        float b0 = yr[u],       i0 = yi[u];               // own t from regs
        float b1 = Br[SK(t1)],  b2 = Br[SK(t2)], b3 = Br[SK(t3)];
        float j1 = Bi[SK(t1)],  j2 = Bi[SK(t2)], j3 = Bi[SK(t3)];
        float e0 = b0*b0, e1 = i0*i0;
        aS0 += e0; aS1 += e1;
        aD00 += e0*e0; aD11 += e1*e1; aD01 += e0*e1;
#pragma unroll
        for (int l = 0; l < 2*P; ++l){
            float el = (u & 1) ? __high2float(est[l][u>>1]) : __low2float(est[l][u>>1]);
            aX[2*l]   += el * e0;
            aX[2*l+1] += el * e1;
        }
        if constexpr (P < 3){
            if ((u & 1) == 0){ carry0 = e0; carry1 = e1; }
            else {
                est[2*P][u>>1]   = __floats2half2_rn(carry0, e0);
                est[2*P+1][u>>1] = __floats2half2_rn(carry1, e1);
            }
        }
        if (t <= TT-4){
            pidR[t] = pattern_id(b0,b1,b2,b3);
            pidI[t] = pattern_id(i0,j1,j2,j3);
        }
    }
    __syncthreads();   // pid writes visible

    // run-length-merged histogram atomics (periodic edge modes collapse to ~1 atomic)
    {
        unsigned* h = hist + 576*((tid>>6) & 1);
        int curR = -1, curI = -1; unsigned cR = 0, cI = 0;
#pragma unroll
        for (int u = 0; u < 8; ++u){
            int t = tid + 512*u;
            if (t <= TT-5){
                int lr = pidR[t]*24 + pidR[t+1];
                if (lr == curR) cR++;
                else { if (cR) atomicAdd(&h[curR], cR); curR = lr; cR = 1; }
                int li = pidI[t]*24 + pidI[t+1];
                if (li == curI) cI++;
                else { if (cI) atomicAdd(&h[curI], cI); curI = li; cI = 1; }
            }
        }
        if (cR) atomicAdd(&h[curR], cR);
        if (cI) atomicAdd(&h[curI], cI);
    }

    const int k0 = 2*P, k1 = 2*P+1;
    reduce_to(aS0,  res, k0, tid);
    reduce_to(aS1,  res, k1, tid);
    reduce_to(aD00, res, DIDX(k0,k0), tid);
    reduce_to(aD11, res, DIDX(k1,k1), tid);
    reduce_to(aD01, res, DIDX(k0,k1), tid);
#pragma unroll
    for (int l = 0; l < 2*P; ++l){
        reduce_to(aX[2*l],   res, DIDX(l,k0), tid);
        reduce_to(aX[2*l+1], res, DIDX(l,k1), tid);
    }
    __syncthreads();   // hist reads of A done -> next pair's stage-0 may write A
}

template<bool DIRECT>
__global__ __launch_bounds__(NTH, 1)     // round-1-proven no-spill config
void fused_kernel(const float* __restrict__ hs, const float* __restrict__ pooled,
                  float* __restrict__ out){
    extern __shared__ float smem[];
    float* Ar = smem;
    float* Ai = smem + ARR;
    float* Br = smem + 2*ARR;
    float* Bi = smem + 3*ARR;
    unsigned* hist = (unsigned*)(smem + 4*ARR);   // 2 x 576
    float* res = smem + 4*ARR + 1152;             // 44

    const int tid = threadIdx.x;
    const int bg = blockIdx.x, b = bg >> 5, g = bg & 31;

    for (int i = tid; i < 1152; i += NTH) hist[i] = 0u;
    if (tid < 44) res[tid] = 0.f;

    // per-thread stage twiddles (inverse sign; fwd passes conj). kk fixed per thread.
    const float PI_F = 3.14159265358979323846f;
    float w8r,w8i,w64r,w64i,w512r,w512i;
    { float s,c;
      __sincosf(PI_F*(float)(tid &  7)/  32.f, &s,&c); w8r=c;   w8i=s;    // 2pi*kk/64
      __sincosf(PI_F*(float)(tid & 63)/ 256.f, &s,&c); w64r=c;  w64i=s;   // 2pi*kk/512
      __sincosf(PI_F*(float)tid       /2048.f, &s,&c); w512r=c; w512i=s;  // 2pi*tid/4096
    }

    // load signal -> A (natural order, skewed)
    if (DIRECT){
        const float* base = hs + ((size_t)b * TT) * 512 + g * 16;
#pragma unroll
        for (int u = 0; u < 8; ++u){
            int t = tid + u*NTH;
            const float4* p = (const float4*)(base + (size_t)t * 512);
            float4 a = p[0], bb = p[1], cc = p[2], dd = p[3];
            float s = a.x+a.y+a.z+a.w + bb.x+bb.y+bb.z+bb.w
                    + cc.x+cc.y+cc.z+cc.w + dd.x+dd.y+dd.z+dd.w;
            Ar[SK(t)] = s * (1.0f/16.0f);
            Ai[SK(t)] = 0.f;
        }
    } else {
        const float* pp = pooled + (size_t)bg * TT;
#pragma unroll
        for (int u = 0; u < 8; ++u){
            int t = tid + u*NTH;
            Ar[SK(t)] = pp[t];
            Ai[SK(t)] = 0.f;
        }
    }
    __syncthreads();

    // forward FFT (numpy sign): 4 radix-8 stages; spectrum lands in registers
    stage8<-1,1>(Ar,Ai,Br,Bi, 1.f,0.f, tid);        __syncthreads();
    stage8<-1,8>(Br,Bi,Ar,Ai, w8r,-w8i, tid);       __syncthreads();
    stage8<-1,64>(Ar,Ai,Br,Bi, w64r,-w64i, tid);    __syncthreads();

    float xr[8], xi[8];   // X[tid + 512*q]
    {
#pragma unroll
        for (int q = 0; q < 8; ++q){
            xr[q] = Br[SK(tid + 512*q)];
            xi[q] = Bi[SK(tid + 512*q)];
        }
        twid8(xr, xi, w512r, -w512i);
        bf8<-1>(xr, xi);
    }
    // no barrier needed: pair-0 stage-0 writes A (last read behind the Ns=64 barrier)

    __half2 est[6][4];
    process_pair<0>(tid,Ar,Ai,Br,Bi,hist,res,xr,xi,est,w8r,w8i,w64r,w64i,w512r,w512i);
    process_pair<1>(tid,Ar,Ai,Br,Bi,hist,res,xr,xi,est,w8r,w8i,w64r,w64i,w512r,w512i);
    process_pair<2>(tid,Ar,Ai,Br,Bi,hist,res,xr,xi,est,w8r,w8i,w64r,w64i,w512r,w512i);
    process_pair<3>(tid,Ar,Ai,Br,Bi,hist,res,xr,xi,est,w8r,w8i,w64r,w64i,w512r,w512i);

    // (process_pair<3> ends with a barrier: hist + res complete)

    float* tm = out + (size_t)bg * 576;
    for (int i = tid; i < 576; i += NTH)
        tm[i] = (float)(hist[i] + hist[i+576]) * (1.0f/32736.0f);

    if (tid < 28){
        int q = tid, k = 0, cnt = 7, rem = q;
        while (rem >= cnt){ rem -= cnt; k++; cnt--; }
        int l = k + 1 + rem;
        float Sk = res[k], Sl = res[l];
        float Dkl = res[DIDX(k,l)], Dkk = res[DIDX(k,k)], Dll = res[DIDX(l,l)];
        float cov = Dkl - Sk*Sl*(1.0f/4096.0f);
        float vk = (Dkk - Sk*Sk*(1.0f/4096.0f)) * (1.0f/4095.0f);
        float vl = (Dll - Sl*Sl*(1.0f/4096.0f)) * (1.0f/4095.0f);
        float sk = fmaxf(sqrtf(fmaxf(vk, 0.f)), 1e-8f);
        float sl = fmaxf(sqrtf(fmaxf(vl, 0.f)), 1e-8f);
        out[294912 + (size_t)bg*28 + q] = cov * (1.0f/4096.0f) / (sk*sl);
    }
}

// Coalesced pooling: [B,T,512] -> [B,G,T] group means (unchanged, verified round 1)
__global__ __launch_bounds__(256)
void pool_kernel(const float* __restrict__ hs, float* __restrict__ pooled){
    __shared__ float tile[32][65];
    int blk = blockIdx.x;               // 16 b * 64 chunks
    int b   = blk >> 6;
    int t0  = (blk & 63) << 6;
    int tid = threadIdx.x;
    int lane = tid & 63, wid = tid >> 6;
#pragma unroll
    for (int i = 0; i < 16; ++i){
        int tl = wid + i*4;
        int t  = t0 + tl;
        const float4* p = (const float4*)(hs + ((size_t)b * TT + t) * 512);
        float4 a = p[lane];
        float4 c = p[lane + 64];
        float pa = a.x+a.y+a.z+a.w;
        float pc = c.x+c.y+c.z+c.w;
        pa += __shfl_xor(pa, 1); pa += __shfl_xor(pa, 2);
        pc += __shfl_xor(pc, 1); pc += __shfl_xor(pc, 2);
        if ((lane & 3) == 0){
            int gq = lane >> 2;
            tile[gq][tl]      = pa * (1.0f/16.0f);
            tile[gq + 16][tl] = pc * (1.0f/16.0f);
        }
    }
    __syncthreads();
    for (int idx = tid; idx < 2048; idx += 256){
        int g = idx >> 6, tt = idx & 63;
        pooled[((size_t)b * 32 + g) * TT + t0 + tt] = tile[g][tt];
    }
}

extern "C" void kernel_launch(void* const* d_in, const int* in_sizes, int n_in,
                              void* d_out, int out_size, void* d_ws, size_t ws_size,
                              hipStream_t stream){
    const float* hs = (const float*)d_in[0];
    float* out = (float*)d_out;
    const size_t poolBytes = (size_t)512 * TT * sizeof(float);   // 8.4 MB

    if (d_ws && ws_size >= poolBytes){
        float* pooled = (float*)d_ws;
        pool_kernel<<<1024, 256, 0, stream>>>(hs, pooled);
        hipFuncSetAttribute((const void*)fused_kernel<false>,
                            hipFuncAttributeMaxDynamicSharedMemorySize, SM_BYTES);
        fused_kernel<false><<<512, NTH, SM_BYTES, stream>>>(hs, pooled, out);
    } else {
        hipFuncSetAttribute((const void*)fused_kernel<true>,
                            hipFuncAttributeMaxDynamicSharedMemorySize, SM_BYTES);
        fused_kernel<true><<<512, NTH, SM_BYTES, stream>>>(hs, nullptr, out);
    }
}